// Round 9
// baseline (312.153 us; speedup 1.0000x reference)
//
#include <hip/hip_runtime.h>

typedef __attribute__((ext_vector_type(8))) short bf16x8;
typedef __attribute__((ext_vector_type(4))) float f32x4;
typedef unsigned short ushort_t;

#define N 4096

__device__ __forceinline__ unsigned short f2bf_rne(float f) {
  unsigned int u = __float_as_uint(f);
  u += 0x7fffu + ((u >> 16) & 1u);
  return (unsigned short)(u >> 16);
}

// One block per row (8192 rows: Z then Y). fp32 row norm + bf16 copy.
__global__ __launch_bounds__(256) void prep_kernel(
    const float* __restrict__ Z, const float* __restrict__ Y,
    ushort_t* __restrict__ Zb, ushort_t* __restrict__ Yb,
    float* __restrict__ norms) {
  const int r = blockIdx.x;
  const bool isZ = (r < N);
  const int rr = isZ ? r : r - N;
  const float* __restrict__ src = (isZ ? Z : Y) + (size_t)rr * N;
  ushort_t* __restrict__ dst = (isZ ? Zb : Yb) + (size_t)rr * N;
  const int t = threadIdx.x;

  float s = 0.f;
#pragma unroll
  for (int j = 0; j < 4; ++j) {
    const float4 v = ((const float4*)src)[j * 256 + t];
    s += v.x * v.x + v.y * v.y + v.z * v.z + v.w * v.w;
    short4 o;
    o.x = (short)f2bf_rne(v.x);
    o.y = (short)f2bf_rne(v.y);
    o.z = (short)f2bf_rne(v.z);
    o.w = (short)f2bf_rne(v.w);
    ((short4*)dst)[j * 256 + t] = o;
  }
#pragma unroll
  for (int off = 32; off > 0; off >>= 1) s += __shfl_down(s, off, 64);
  __shared__ float red[4];
  const int lane = t & 63, w = t >> 6;
  if (lane == 0) red[w] = s;
  __syncthreads();
  if (t == 0) norms[r] = sqrtf(red[0] + red[1] + red[2] + red[3]);
}

// ---- 256x256 tile, 8 waves (2M x 4N), K-tiles of 64 ---------------------
// B staged in LDS (ring-2, 32KB/buf, swizzle slot ^= row&7, conflict-free).
// A-fragments loaded DIRECTLY global->register (L2-resident; 16x16x32 A-frag
// pattern = 16 rows x 16B per instr), double-buffered across K-32 steps.
// One barrier + one vmcnt(0) per K-tile; everything outstanding at the
// drain is consumed next tile (stage B(t+1), A(t+1,h0)) -> cheap drain.
__global__ __launch_bounds__(512, 2) void gemm_kernel(
    const ushort_t* __restrict__ A,   // Zb [N][N]
    const ushort_t* __restrict__ B,   // Yb [N][N]
    const float* __restrict__ norms,  // [2N]: nx then ny
    float* __restrict__ out) {
  __shared__ __align__(16) char smem[65536];   // 2 x 32KB B bufs

  const int bid = blockIdx.x;                 // 256 blocks; bijective
  const int swz = (bid & 7) * 32 + (bid >> 3);
  const int tile_row = swz >> 4;
  const int tile_col = swz & 15;

  const int tid = threadIdx.x;
  const int l = tid & 63;
  const int w = tid >> 6;
  const int wr = w >> 2;      // M half (128 rows)
  const int wc = w & 3;       // N quarter (64 cols)
  const int li = l & 15;
  const int sl = l >> 4;

  // ---- B staging: 4 GLD/thread per K-tile (32KB = 256 rows x 128B) ------
  // chunk ch = q*512 + tid -> LDS byte ch*16 (linear); LDS(row,slot) holds
  // global(row, slot ^ (row&7)); row = ch>>3, slot = ch&7 (16B units).
  const ushort_t* pgB[4];
#pragma unroll
  for (int q = 0; q < 4; ++q) {
    const int ch = q * 512 + tid;
    const int row = ch >> 3;                   // 0..255
    const int scol = ((ch & 7) ^ (row & 7)) * 8;
    pgB[q] = B + (size_t)(tile_col * 256 + row) * N + scol;
  }
#define GLD(SRC, DST)                                              \
  __builtin_amdgcn_global_load_lds(                                \
      (__attribute__((address_space(1))) void*)(SRC),              \
      (__attribute__((address_space(3))) void*)(DST), 16, 0, 0)
#define STG_B(T_, BUFB) { _Pragma("unroll")                        \
    for (int q = 0; q < 4; ++q)                                    \
      GLD(pgB[q] + (T_) * 64, smem + (BUFB) + q * 8192 + w * 1024); }

  // ---- B fragment reads: row = wc*64 + nf*16 + li (row&7 == li&7) -------
  int offB[4];
#pragma unroll
  for (int nf = 0; nf < 4; ++nf) offB[nf] = (wc * 64 + nf * 16 + li) * 128;
  const int sb[2] = { ((0 * 4 + sl) ^ (li & 7)) * 16,
                      ((1 * 4 + sl) ^ (li & 7)) * 16 };

  // ---- A direct-load base: lane reads row wr*128 + m*16 + li, 16B @ sl*8
  const ushort_t* pa =
      A + (size_t)(tile_row * 256 + wr * 128 + li) * N + sl * 8;

  bf16x8 a0[8], a1[8], bF[4];
  f32x4 acc[8][4];
#pragma unroll
  for (int m = 0; m < 8; ++m)
#pragma unroll
    for (int n = 0; n < 4; ++n) acc[m][n] = (f32x4){0.f, 0.f, 0.f, 0.f};

#define LDA(DST, KK) { _Pragma("unroll")                                      \
    for (int m = 0; m < 8; ++m)                                               \
      DST[m] = *(const bf16x8*)(pa + (size_t)m * 16 * N + (KK)); }

#define SB  __builtin_amdgcn_sched_barrier(0);
#define LG  { asm volatile("s_waitcnt lgkmcnt(0)" ::: "memory"); SB; }
#define VM0 asm volatile("s_waitcnt vmcnt(0)" ::: "memory");

  // 32 MFMA on one K-32 step: frags AF x bF
#define STEP(AF, BUFB, H) {                                                   \
    _Pragma("unroll")                                                         \
    for (int nf = 0; nf < 4; ++nf)                                            \
      bF[nf] = *(const bf16x8*)(smem + (BUFB) + offB[nf] + sb[H]);            \
    LG;                                                                       \
    __builtin_amdgcn_s_setprio(1);                                            \
    _Pragma("unroll") for (int m = 0; m < 8; ++m)                             \
    _Pragma("unroll") for (int n = 0; n < 4; ++n)                             \
      acc[m][n] = __builtin_amdgcn_mfma_f32_16x16x32_bf16(                    \
          AF[m], bF[n], acc[m][n], 0, 0, 0);                                  \
    __builtin_amdgcn_s_setprio(0); }

  // per K-tile T (buf BUFB): step0 computes a0/(T,h0), step1 a1/(T,h1).
#define TILE(T_, BUFB, DOSTG, DOPREF, DOSYNC) {                               \
    if (DOSTG) STG_B((T_) + 1, (BUFB) ^ 32768);                               \
    LDA(a1, (T_) * 64 + 32);                                                  \
    SB;                                                                       \
    STEP(a0, BUFB, 0);                                                        \
    if (DOPREF) LDA(a0, ((T_) + 1) * 64);                                     \
    SB;                                                                       \
    STEP(a1, BUFB, 1);                                                        \
    if (DOSYNC) {                                                             \
      VM0;                                                                    \
      __builtin_amdgcn_s_barrier();                                           \
      SB;                                                                     \
    } }

  // prologue: stage B(0) -> buf0, load a0(0,h0); drain; barrier
  STG_B(0, 0);
  LDA(a0, 0);
  VM0;
  __builtin_amdgcn_s_barrier();
  SB;

  // 64 K-tiles total (K = 4096 = 64 x 64)
  for (int tt = 0; tt < 62; tt += 2) {
    TILE(tt, 0, true, true, true);
    TILE(tt + 1, 32768, true, true, true);
  }
  TILE(62, 0, true, true, true);
  TILE(63, 32768, false, false, false);
#undef TILE

  // ---- epilogue: cosine normalize; C/D layout row=(l>>4)*4+r, col=l&15 --
  const float* nx = norms;
  const float* ny = norms + N;
  const int row0 = tile_row * 256 + wr * 128 + sl * 4;
  const int col0 = tile_col * 256 + wc * 64 + li;
#pragma unroll
  for (int m = 0; m < 8; ++m) {
#pragma unroll
    for (int r = 0; r < 4; ++r) {
      const int row = row0 + m * 16 + r;
      const float nxr = nx[row];
#pragma unroll
      for (int n = 0; n < 4; ++n) {
        const int col = col0 + n * 16;
        const float denom = fmaxf(nxr * ny[col], 1e-8f);
        out[(size_t)row * N + col] = acc[m][n][r] / denom;
      }
    }
  }
}

extern "C" void kernel_launch(void* const* d_in, const int* in_sizes, int n_in,
                              void* d_out, int out_size, void* d_ws, size_t ws_size,
                              hipStream_t stream) {
  const float* Z = (const float*)d_in[0];
  const float* Y = (const float*)d_in[1];
  float* out = (float*)d_out;

  ushort_t* Zb = (ushort_t*)d_ws;
  ushort_t* Yb = Zb + (size_t)N * N;
  float* norms = (float*)(Yb + (size_t)N * N);

  prep_kernel<<<2 * N, 256, 0, stream>>>(Z, Y, Zb, Yb, norms);
  gemm_kernel<<<(N / 256) * (N / 256), 512, 0, stream>>>(Zb, Yb, norms, out);
}

// Round 10
// 179.939 us; speedup vs baseline: 1.7348x; 1.7348x over previous
//
#include <hip/hip_runtime.h>

typedef __attribute__((ext_vector_type(8))) short bf16x8;
typedef __attribute__((ext_vector_type(4))) float f32x4;
typedef unsigned short ushort_t;

#define N 4096

__device__ __forceinline__ unsigned short f2bf_rne(float f) {
  unsigned int u = __float_as_uint(f);
  u += 0x7fffu + ((u >> 16) & 1u);
  return (unsigned short)(u >> 16);
}

// One block per row (8192 rows: Z then Y). fp32 row norm + bf16 copy.
__global__ __launch_bounds__(256) void prep_kernel(
    const float* __restrict__ Z, const float* __restrict__ Y,
    ushort_t* __restrict__ Zb, ushort_t* __restrict__ Yb,
    float* __restrict__ norms) {
  const int r = blockIdx.x;
  const bool isZ = (r < N);
  const int rr = isZ ? r : r - N;
  const float* __restrict__ src = (isZ ? Z : Y) + (size_t)rr * N;
  ushort_t* __restrict__ dst = (isZ ? Zb : Yb) + (size_t)rr * N;
  const int t = threadIdx.x;

  float s = 0.f;
#pragma unroll
  for (int j = 0; j < 4; ++j) {
    const float4 v = ((const float4*)src)[j * 256 + t];
    s += v.x * v.x + v.y * v.y + v.z * v.z + v.w * v.w;
    short4 o;
    o.x = (short)f2bf_rne(v.x);
    o.y = (short)f2bf_rne(v.y);
    o.z = (short)f2bf_rne(v.z);
    o.w = (short)f2bf_rne(v.w);
    ((short4*)dst)[j * 256 + t] = o;
  }
#pragma unroll
  for (int off = 32; off > 0; off >>= 1) s += __shfl_down(s, off, 64);
  __shared__ float red[4];
  const int lane = t & 63, w = t >> 6;
  if (lane == 0) red[w] = s;
  __syncthreads();
  if (t == 0) norms[r] = sqrtf(red[0] + red[1] + red[2] + red[3]);
}

// ---- 256x128 tile, BK=32, 8 waves (2M x 4N), ring-3 LDS, 2 blocks/CU ----
// LDS per buf (24KB): A [256][32] @0 (16KB), B [128][32] @16384 (8KB);
// bufs at 0 / 24576 / 49152 (72KB total -> 2 blocks co-resident per CU).
// Row = 64B = 4 slots of 16B; swizzle slot ^= (row & 3)  [involution].
// Per K-tile: {10 ds_read_b128 | stage T+2 (3 GLD)} -> barrier -> lgkm0 ->
// 16 MFMA -> vmcnt(3) -> barrier. Cross-block TLP fills barrier stalls.
__global__ __launch_bounds__(512, 4) void gemm_kernel(
    const ushort_t* __restrict__ A,   // Zb [N][N]
    const ushort_t* __restrict__ B,   // Yb [N][N]
    const float* __restrict__ norms,  // [2N]: nx then ny
    float* __restrict__ out) {
  __shared__ __align__(16) char smem[73728];

  const int bid = blockIdx.x;                 // 512 blocks; 512%8==0 bijective
  const int swz = (bid & 7) * 64 + (bid >> 3);
  const int tile_row = swz >> 5;              // 0..15
  const int tile_col = swz & 31;              // 0..31

  const int tid = threadIdx.x;
  const int l = tid & 63;
  const int w = tid >> 6;
  const int wr = w >> 2;      // M half (128 rows)
  const int wc = w & 3;       // N quarter (32 cols)
  const int li = l & 15;
  const int sl = l >> 4;

  // ---- staging pointers (pre-swizzled global sources) -------------------
  // A: chunk ch = q*512+tid -> LDS byte ch*16 in region [256][32];
  //    row = ch>>2, slot = ch&3; src col = (slot ^ (row&3))*8.
  const ushort_t* pgA[2];
#pragma unroll
  for (int q = 0; q < 2; ++q) {
    const int ch = q * 512 + tid;
    const int row = ch >> 2;
    const int scol = (((ch & 3) ^ (row & 3)) * 8);
    pgA[q] = A + (size_t)(tile_row * 256 + row) * N + scol;
  }
  // B: chunk = tid -> region [128][32]; row = tid>>2, slot = tid&3.
  const ushort_t* pgB;
  {
    const int row = tid >> 2;
    const int scol = (((tid & 3) ^ (row & 3)) * 8);
    pgB = B + (size_t)(tile_col * 128 + row) * N + scol;
  }

#define GLD(SRC, DST)                                              \
  __builtin_amdgcn_global_load_lds(                                \
      (__attribute__((address_space(1))) void*)(SRC),              \
      (__attribute__((address_space(3))) void*)(DST), 16, 0, 0)
#define STG(T_, BUFB) {                                                     \
    GLD(pgA[0] + (T_) * 32, smem + (BUFB) + w * 1024);                      \
    GLD(pgA[1] + (T_) * 32, smem + (BUFB) + 8192 + w * 1024);               \
    GLD(pgB + (T_) * 32, smem + (BUFB) + 16384 + w * 1024); }

  // ---- fragment offsets (bytes within a buf) ----------------------------
  // lane reads row base+li, 16B slot sl, swizzled slot = sl ^ (li&3)
  const int ssl = (sl ^ (li & 3)) * 16;
  int offA[8], offB[2];
#pragma unroll
  for (int m = 0; m < 8; ++m)
    offA[m] = (wr * 128 + m * 16 + li) * 64 + ssl;
#pragma unroll
  for (int nf = 0; nf < 2; ++nf)
    offB[nf] = 16384 + (wc * 32 + nf * 16 + li) * 64 + ssl;

  f32x4 acc[8][2];
#pragma unroll
  for (int m = 0; m < 8; ++m)
#pragma unroll
    for (int n = 0; n < 2; ++n) acc[m][n] = (f32x4){0.f, 0.f, 0.f, 0.f};

#define SB  __builtin_amdgcn_sched_barrier(0);
#define VM3 asm volatile("s_waitcnt vmcnt(3)" ::: "memory");
#define VM0 asm volatile("s_waitcnt vmcnt(0)" ::: "memory");

  // per K-tile body
#define TILE(T_, CURB, STGB, DOSTG, VMN) {                                    \
    bf16x8 aF[8], bF[2];                                                      \
    _Pragma("unroll")                                                         \
    for (int m = 0; m < 8; ++m)                                               \
      aF[m] = *(const bf16x8*)(smem + (CURB) + offA[m]);                      \
    _Pragma("unroll")                                                         \
    for (int n = 0; n < 2; ++n)                                               \
      bF[n] = *(const bf16x8*)(smem + (CURB) + offB[n]);                      \
    if (DOSTG) STG((T_) + 2, STGB);                                           \
    __builtin_amdgcn_s_barrier();                                             \
    asm volatile("s_waitcnt lgkmcnt(0)" ::: "memory");                        \
    SB;                                                                       \
    __builtin_amdgcn_s_setprio(1);                                            \
    _Pragma("unroll")                                                         \
    for (int m = 0; m < 8; ++m)                                               \
      _Pragma("unroll")                                                       \
      for (int n = 0; n < 2; ++n)                                             \
        acc[m][n] = __builtin_amdgcn_mfma_f32_16x16x32_bf16(                  \
            aF[m], bF[n], acc[m][n], 0, 0, 0);                                \
    __builtin_amdgcn_s_setprio(0);                                            \
    if ((VMN) == 3) { VM3; }                                                  \
    else if ((VMN) == 0) { VM0; }                                             \
    if ((VMN) >= 0) { __builtin_amdgcn_s_barrier(); SB; }                     \
  }

  // prologue: stage T0 -> buf0, T1 -> buf1; wait T0; barrier
  STG(0, 0);
  STG(1, 24576);
  VM3;
  __builtin_amdgcn_s_barrier();
  SB;

  // 128 K-tiles; ring-3: cur = T%3, stage T+2 -> (T+2)%3
  for (int t = 0; t < 126; t += 3) {
    TILE(t, 0, 49152, true, 3);
    TILE(t + 1, 24576, 0, true, 3);
    TILE(t + 2, 49152, 24576, true, 3);
  }
  TILE(126, 0, 0, false, 0);        // gate vmcnt(0): T127 resident
  TILE(127, 24576, 0, false, -1);   // final: no stage, no gate
#undef TILE

  // ---- epilogue: cosine normalize; C/D layout row=(l>>4)*4+r, col=l&15 --
  const float* nx = norms;
  const float* ny = norms + N;
  const int row0 = tile_row * 256 + wr * 128 + sl * 4;
  const int col0 = tile_col * 128 + wc * 32 + li;
#pragma unroll
  for (int m = 0; m < 8; ++m) {
#pragma unroll
    for (int r = 0; r < 4; ++r) {
      const int row = row0 + m * 16 + r;
      const float nxr = nx[row];
#pragma unroll
      for (int n = 0; n < 2; ++n) {
        const int col = col0 + n * 16;
        const float denom = fmaxf(nxr * ny[col], 1e-8f);
        out[(size_t)row * N + col] = acc[m][n][r] / denom;
      }
    }
  }
}

extern "C" void kernel_launch(void* const* d_in, const int* in_sizes, int n_in,
                              void* d_out, int out_size, void* d_ws, size_t ws_size,
                              hipStream_t stream) {
  const float* Z = (const float*)d_in[0];
  const float* Y = (const float*)d_in[1];
  float* out = (float*)d_out;

  ushort_t* Zb = (ushort_t*)d_ws;
  ushort_t* Yb = Zb + (size_t)N * N;
  float* norms = (float*)(Yb + (size_t)N * N);

  prep_kernel<<<2 * N, 256, 0, stream>>>(Z, Y, Zb, Yb, norms);
  gemm_kernel<<<(N / 256) * (N / 128), 512, 0, stream>>>(Zb, Yb, norms, out);
}

// Round 11
// 142.403 us; speedup vs baseline: 2.1920x; 1.2636x over previous
//
#include <hip/hip_runtime.h>

typedef __attribute__((ext_vector_type(8))) short bf16x8;
typedef __attribute__((ext_vector_type(4))) float f32x4;
typedef unsigned short ushort_t;

#define N 4096

__device__ __forceinline__ unsigned short f2bf_rne(float f) {
  unsigned int u = __float_as_uint(f);
  u += 0x7fffu + ((u >> 16) & 1u);
  return (unsigned short)(u >> 16);
}

// One block per row (8192 rows: Z then Y). fp32 row norm + bf16 copy.
__global__ __launch_bounds__(256) void prep_kernel(
    const float* __restrict__ Z, const float* __restrict__ Y,
    ushort_t* __restrict__ Zb, ushort_t* __restrict__ Yb,
    float* __restrict__ norms) {
  const int r = blockIdx.x;
  const bool isZ = (r < N);
  const int rr = isZ ? r : r - N;
  const float* __restrict__ src = (isZ ? Z : Y) + (size_t)rr * N;
  ushort_t* __restrict__ dst = (isZ ? Zb : Yb) + (size_t)rr * N;
  const int t = threadIdx.x;

  float s = 0.f;
#pragma unroll
  for (int j = 0; j < 4; ++j) {
    const float4 v = ((const float4*)src)[j * 256 + t];
    s += v.x * v.x + v.y * v.y + v.z * v.z + v.w * v.w;
    short4 o;
    o.x = (short)f2bf_rne(v.x);
    o.y = (short)f2bf_rne(v.y);
    o.z = (short)f2bf_rne(v.z);
    o.w = (short)f2bf_rne(v.w);
    ((short4*)dst)[j * 256 + t] = o;
  }
#pragma unroll
  for (int off = 32; off > 0; off >>= 1) s += __shfl_down(s, off, 64);
  __shared__ float red[4];
  const int lane = t & 63, w = t >> 6;
  if (lane == 0) red[w] = s;
  __syncthreads();
  if (t == 0) norms[r] = sqrtf(red[0] + red[1] + red[2] + red[3]);
}

// ---- 256x256 tile, BK=64, 8 waves, 2-deep dbuf, 8-phase -----------------
// NEW vs r4: reads pipelined ONE PHASE AHEAD with COUNTED lgkmcnt (never
// wait the reads just issued), pinned by sched_barrier. Quadrant order
// Q00,Q01,Q11,Q10 (B-major gray) -> single shared A-frag set (64 VGPR).
// Wave (wr,wc): A-qh QH rows = QH*128 + wr*64 + [0,64); B-qh rows =
// QH*128 + wc*32 + [0,32). Regions per buf: A0@0 A1@16K B0@32K B1@48K.
// Stage 1 region (16KB, 2 GLD/wave) per phase; uniform vmcnt(2) gates.
__global__ __launch_bounds__(512, 2) void gemm_kernel(
    const ushort_t* __restrict__ A,   // Zb [N][N]
    const ushort_t* __restrict__ B,   // Yb [N][N]
    const float* __restrict__ norms,  // [2N]: nx then ny
    float* __restrict__ out) {
  __shared__ __align__(16) char smem[131072];

  const int bid = blockIdx.x;                 // 256 blocks; bijective
  const int swz = (bid & 7) * 32 + (bid >> 3);
  const int tile_row = swz >> 4;
  const int tile_col = swz & 15;

  const int tid = threadIdx.x;
  const int l = tid & 63;
  const int w = tid >> 6;
  const int wr = w >> 2;      // 0..1
  const int wc = w & 3;       // 0..3
  const int li = l & 15;
  const int sl = l >> 4;

  // ---- staging pointers: 8 per-thread pre-swizzled sources --------------
  // chunk ch = q*512+tid -> LDS byte ch*16 of a 16KB region (128 rows x
  // 128B); LDS(row,slot) holds global(row, slot^(row&7)).
  const ushort_t *pA00, *pA01, *pA10, *pA11, *pB00, *pB01, *pB10, *pB11;
  {
    const int ch0 = tid, ch1 = 512 + tid;
    const int r0 = ch0 >> 3, r1 = ch1 >> 3;
    const int c0 = ((ch0 & 7) ^ (r0 & 7)) * 8;
    const int c1 = ((ch1 & 7) ^ (r1 & 7)) * 8;
    pA00 = A + (size_t)(tile_row * 256 + r0) * N + c0;
    pA01 = A + (size_t)(tile_row * 256 + r1) * N + c1;
    pA10 = A + (size_t)(tile_row * 256 + 128 + r0) * N + c0;
    pA11 = A + (size_t)(tile_row * 256 + 128 + r1) * N + c1;
    pB00 = B + (size_t)(tile_col * 256 + r0) * N + c0;
    pB01 = B + (size_t)(tile_col * 256 + r1) * N + c1;
    pB10 = B + (size_t)(tile_col * 256 + 128 + r0) * N + c0;
    pB11 = B + (size_t)(tile_col * 256 + 128 + r1) * N + c1;
  }

#define GLD(SRC, DST)                                              \
  __builtin_amdgcn_global_load_lds(                                \
      (__attribute__((address_space(1))) void*)(SRC),              \
      (__attribute__((address_space(3))) void*)(DST), 16, 0, 0)
#define STG(REGOFF, P0, P1, KOFF) {                                \
    GLD((P0) + (KOFF), smem + (REGOFF) + w * 1024);                \
    GLD((P1) + (KOFF), smem + (REGOFF) + 8192 + w * 1024); }

  // ---- fragment addressing ----------------------------------------------
  const int rbA = (wr * 64 + li) * 128;   // + QH*16384 region + mfl*2048
  const int rbB = (wc * 32 + li) * 128;   // + 32768 + QH*16384 + nfl*2048
  const int sx0 = ((sl) ^ (li & 7)) * 16;
  const int sx1 = ((4 + sl) ^ (li & 7)) * 16;

  bf16x8 aC[4][2], bQ0[2][2], bQ1[2][2];
  f32x4 acc[8][4];
#pragma unroll
  for (int m = 0; m < 8; ++m)
#pragma unroll
    for (int n = 0; n < 4; ++n) acc[m][n] = (f32x4){0.f, 0.f, 0.f, 0.f};

#define RD_A(BUFB, QH) { _Pragma("unroll")                                    \
    for (int mfl = 0; mfl < 4; ++mfl) {                                       \
      aC[mfl][0] = *(const bf16x8*)(smem + (BUFB) + (QH)*16384 + rbA +        \
                                    mfl*2048 + sx0);                          \
      aC[mfl][1] = *(const bf16x8*)(smem + (BUFB) + (QH)*16384 + rbA +        \
                                    mfl*2048 + sx1); } }
#define RD_B(DST, BUFB, QH) { _Pragma("unroll")                               \
    for (int nfl = 0; nfl < 2; ++nfl) {                                       \
      DST[nfl][0] = *(const bf16x8*)(smem + (BUFB) + 32768 + (QH)*16384 +     \
                                     rbB + nfl*2048 + sx0);                   \
      DST[nfl][1] = *(const bf16x8*)(smem + (BUFB) + 32768 + (QH)*16384 +     \
                                     rbB + nfl*2048 + sx1); } }

#define MFQ(QM, QN, BF) {                                                     \
    __builtin_amdgcn_s_setprio(1);                                            \
    _Pragma("unroll") for (int kh = 0; kh < 2; ++kh)                          \
    _Pragma("unroll") for (int mfl = 0; mfl < 4; ++mfl)                       \
    _Pragma("unroll") for (int nfl = 0; nfl < 2; ++nfl)                       \
      acc[(QM)*4+mfl][(QN)*2+nfl] = __builtin_amdgcn_mfma_f32_16x16x32_bf16(  \
          aC[mfl][kh], BF[nfl][kh], acc[(QM)*4+mfl][(QN)*2+nfl], 0, 0, 0);    \
    __builtin_amdgcn_s_setprio(0); }

#define SB   __builtin_amdgcn_sched_barrier(0);
#define BAR  __builtin_amdgcn_s_barrier();
#define VMW2 asm volatile("s_waitcnt vmcnt(2)" ::: "memory");
#define VMW4 asm volatile("s_waitcnt vmcnt(4)" ::: "memory");
#define VMW0 asm volatile("s_waitcnt vmcnt(0)" ::: "memory");
#define LGW4 { asm volatile("s_waitcnt lgkmcnt(4)" ::: "memory"); SB }
#define LGW0 { asm volatile("s_waitcnt lgkmcnt(0)" ::: "memory"); SB }

  // ---- prologue: stage T0 (A0,B0,B1,A1 order), gate A0/B0, prime q0 -----
  STG(0, pA00, pA01, 0);          // A0(T0)
  STG(32768, pB00, pB01, 0);      // B0(T0)
  STG(49152, pB10, pB11, 0);      // B1(T0)
  STG(16384, pA10, pA11, 0);      // A1(T0)
  VMW4; BAR; SB;
  RD_A(0, 0); RD_B(bQ0, 0, 0);    // 12 reads: q0(T0)

  // ---- main loop: iter k = tiles 2k (buf0), 2k+1 (buf1) -----------------
#pragma unroll 1
  for (int k = 0; k < 31; ++k) {
    // ph1: Q00(T)
    VMW2; BAR; SB;
    RD_B(bQ1, 0, 1);                       // 4: Bq1(T)
    STG(65536, pA00, pA01, 64);            // A0(T+1)
    LGW4;
    MFQ(0, 0, bQ0);
    // ph2: Q01(T)
    VMW2; BAR;
    STG(98304, pB00, pB01, 64);            // B0(T+1)
    LGW0;
    MFQ(0, 1, bQ1);
    SB;
    RD_A(0, 1);                            // 8: Aq1(T) -> aC
    // ph3: Q11(T)
    BAR;
    STG(114688, pB10, pB11, 64);           // B1(T+1)
    LGW0;
    MFQ(1, 1, bQ1);
    // ph4: Q10(T)
    VMW2; BAR;
    STG(81920, pA10, pA11, 64);            // A1(T+1)
    MFQ(1, 0, bQ0);
    SB;
    RD_A(65536, 0); RD_B(bQ0, 65536, 0);   // 12: q0(T+1)
    // ph5: Q00(T+1)
    VMW2; BAR; SB;
    RD_B(bQ1, 65536, 1);                   // 4: Bq1(T+1)
    STG(0, pA00, pA01, 128);               // A0(T+2)
    LGW4;
    MFQ(0, 0, bQ0);
    // ph6: Q01(T+1)
    VMW2; BAR;
    STG(32768, pB00, pB01, 128);           // B0(T+2)
    LGW0;
    MFQ(0, 1, bQ1);
    SB;
    RD_A(65536, 1);                        // 8: Aq1(T+1)
    // ph7: Q11(T+1)
    BAR;
    STG(49152, pB10, pB11, 128);           // B1(T+2)
    LGW0;
    MFQ(1, 1, bQ1);
    // ph8: Q10(T+1)
    VMW2; BAR;
    STG(16384, pA10, pA11, 128);           // A1(T+2)
    MFQ(1, 0, bQ0);
    SB;
    RD_A(0, 0); RD_B(bQ0, 0, 0);           // 12: q0(T+2)
    // advance staging pointers by 2 K-tiles (128 elements)
    pA00 += 128; pA01 += 128; pA10 += 128; pA11 += 128;
    pB00 += 128; pB01 += 128; pB10 += 128; pB11 += 128;
  }

  // ---- tail: tiles 62 (buf0), 63 (buf1); stage only T63 -----------------
  // t-ph1
  VMW2; BAR; SB;
  RD_B(bQ1, 0, 1);
  STG(65536, pA00, pA01, 64);
  LGW4;
  MFQ(0, 0, bQ0);
  // t-ph2
  VMW2; BAR;
  STG(98304, pB00, pB01, 64);
  LGW0;
  MFQ(0, 1, bQ1);
  SB;
  RD_A(0, 1);
  // t-ph3
  BAR;
  STG(114688, pB10, pB11, 64);
  LGW0;
  MFQ(1, 1, bQ1);
  // t-ph4
  VMW2; BAR;
  STG(81920, pA10, pA11, 64);
  MFQ(1, 0, bQ0);
  SB;
  RD_A(65536, 0); RD_B(bQ0, 65536, 0);
  // t-ph5
  VMW2; BAR; SB;
  RD_B(bQ1, 65536, 1);
  LGW4;
  MFQ(0, 0, bQ0);
  // t-ph6
  VMW0; BAR;
  LGW0;
  MFQ(0, 1, bQ1);
  SB;
  RD_A(65536, 1);
  // t-ph7
  LGW0;
  MFQ(1, 1, bQ1);
  // t-ph8
  MFQ(1, 0, bQ0);

  // ---- epilogue: cosine normalize ---------------------------------------
  // acc[mf][nf]: row = tr*256 + (mf>>2)*128 + wr*64 + (mf&3)*16 + sl*4 + r
  //              col = tc*256 + (nf>>1)*128 + wc*32 + (nf&1)*16 + li
  const float* nx = norms;
  const float* ny = norms + N;
#pragma unroll
  for (int mf = 0; mf < 8; ++mf) {
#pragma unroll
    for (int r = 0; r < 4; ++r) {
      const int row = tile_row * 256 + (mf >> 2) * 128 + wr * 64 +
                      (mf & 3) * 16 + sl * 4 + r;
      const float nxr = nx[row];
#pragma unroll
      for (int nf = 0; nf < 4; ++nf) {
        const int col = tile_col * 256 + (nf >> 1) * 128 + wc * 32 +
                        (nf & 1) * 16 + li;
        const float denom = fmaxf(nxr * ny[col], 1e-8f);
        out[(size_t)row * N + col] = acc[mf][nf][r] / denom;
      }
    }
  }
}

extern "C" void kernel_launch(void* const* d_in, const int* in_sizes, int n_in,
                              void* d_out, int out_size, void* d_ws, size_t ws_size,
                              hipStream_t stream) {
  const float* Z = (const float*)d_in[0];
  const float* Y = (const float*)d_in[1];
  float* out = (float*)d_out;

  ushort_t* Zb = (ushort_t*)d_ws;
  ushort_t* Yb = Zb + (size_t)N * N;
  float* norms = (float*)(Yb + (size_t)N * N);

  prep_kernel<<<2 * N, 256, 0, stream>>>(Z, Y, Zb, Yb, norms);
  gemm_kernel<<<(N / 256) * (N / 256), 512, 0, stream>>>(Zb, Yb, norms, out);
}